// Round 8
// baseline (231.422 us; speedup 1.0000x reference)
//
#include <hip/hip_runtime.h>
#include <math.h>

// Problem constants
#define BDIM 4
#define GDIM 40
#define CDIM 13
#define TDIM 1024
#define FDIM 513                 // T/2 + 1
#define BG   (BDIM*GDIM)         // 160
#define NROW (BG*FDIM)           // 82080 rows of [13] complex
#define NCHUNK 9                 // 9*64 = 576 >= 513 q-rows per bg

typedef _Float16 half4 __attribute__((ext_vector_type(4)));
typedef _Float16 half8 __attribute__((ext_vector_type(8)));
typedef float    f32x4 __attribute__((ext_vector_type(4)));

#define MFMA16(a, b, c) __builtin_amdgcn_mfma_f32_16x16x16f16((a), (b), (c), 0, 0, 0)
#define MFMA32(a, b, c) __builtin_amdgcn_mfma_f32_16x16x32_f16((a), (b), (c), 0, 0, 0)

__device__ __forceinline__ unsigned bitrev10(unsigned x) { return __brev(x) >> 22; }

// ---------------- Kernel 1: two-for-one rfft(1024) ----------------
// Launched with 512 threads: 1 butterfly per thread per stage, 8 waves/block.
__global__ void fft_fwd2(const float* __restrict__ x, float2* __restrict__ xf) {
    __shared__ float re[1024], im[1024];
    const int s2 = blockIdx.x;                   // pair index, 0..1039
    const float* x1 = x + (size_t)(2 * s2) * TDIM;
    const float* x2 = x1 + TDIM;
    for (int t = threadIdx.x; t < 1024; t += blockDim.x) {
        unsigned r = bitrev10(t);
        re[r] = x1[t];
        im[r] = x2[t];
    }
    __syncthreads();
    for (int s = 0; s < 10; ++s) {
        int half = 1 << s;
        for (int j = threadIdx.x; j < 512; j += blockDim.x) {
            int grp = j >> s;
            int pos = j & (half - 1);
            int i1 = (grp << (s + 1)) + pos;
            int i2 = i1 + half;
            float ang = -(float)M_PI * (float)pos / (float)half;
            float sw, cw; __sincosf(ang, &sw, &cw);
            float xr = re[i2], xi = im[i2];
            float tr = cw * xr - sw * xi;
            float ti = cw * xi + sw * xr;
            float ur = re[i1], ui = im[i1];
            re[i1] = ur + tr; im[i1] = ui + ti;
            re[i2] = ur - tr; im[i2] = ui - ti;
        }
        __syncthreads();
    }
    const int sigA = 2 * s2, sigB = sigA + 1;
    const int bgA = sigA / CDIM, cA = sigA % CDIM;
    const int bgB = sigB / CDIM, cB = sigB % CDIM;
    for (int f = threadIdx.x; f < FDIM; f += blockDim.x) {
        int fr = (1024 - f) & 1023;
        float zr = re[f], zi = im[f];
        float wr = re[fr], wi = im[fr];
        xf[((size_t)bgA * FDIM + f) * CDIM + cA] =
            make_float2(0.5f * (zr + wr), 0.5f * (zi - wi));
        xf[((size_t)bgB * FDIM + f) * CDIM + cB] =
            make_float2(0.5f * (zi + wi), 0.5f * (wr - zr));
    }
}

// ---------------- Kernel 2: Q/K/V projections ----------------
// q: float2 rows (for in-reg Q-fragment build in attn).
// KP: per row 64 halves [hi(kr)0..12 | hi(ki)@13..25 | 0 @26..31 | lo(kr)@32..44 | lo(ki)@45..57 | 0 @58..63]
// VT: fp16, transposed: [bg][re/im][c(16)][f stride 520]
__global__ void qkv_kernel(const float2* __restrict__ xf,
                           const float* __restrict__ wq,
                           const float* __restrict__ wk,
                           const float* __restrict__ wv,
                           float2* __restrict__ q,
                           _Float16* __restrict__ KP,
                           _Float16* __restrict__ VT) {
    int gid = blockIdx.x * blockDim.x + threadIdx.x;
    if (gid >= NROW * CDIM) return;
    int r = gid / CDIM;
    int i = gid - r * CDIM;
    const float2* xrow = xf + (size_t)r * CDIM;
    float qr = 0, qi = 0, kr = 0, ki = 0, vr = 0, vi = 0;
#pragma unroll
    for (int c = 0; c < CDIM; ++c) {
        float2 xc = xrow[c];
        float a = wq[c * CDIM + i]; qr += xc.x * a; qi += xc.y * a;
        float b = wk[c * CDIM + i]; kr += xc.x * b; ki += xc.y * b;
        float d = wv[c * CDIM + i]; vr += xc.x * d; vi += xc.y * d;
    }
    q[gid] = make_float2(qr, qi);

    _Float16* krow = KP + (size_t)r * 64;
    _Float16 h0 = (_Float16)kr;
    _Float16 h1 = (_Float16)ki;
    krow[i]      = h0;
    krow[13 + i] = h1;
    krow[32 + i] = (_Float16)(kr - (float)h0);
    krow[45 + i] = (_Float16)(ki - (float)h1);
    if (i == 12) {   // zero the pad halves 26..31 and 58..63
        *(unsigned int*)(krow + 26) = 0u;
        *(unsigned int*)(krow + 28) = 0u;
        *(unsigned int*)(krow + 30) = 0u;
        *(unsigned int*)(krow + 58) = 0u;
        *(unsigned int*)(krow + 60) = 0u;
        *(unsigned int*)(krow + 62) = 0u;
    }
    int bg = r / FDIM;
    int f  = r - bg * FDIM;
    VT[((size_t)(bg * 2 + 0) * 16 + i) * 520 + f] = (_Float16)vr;
    VT[((size_t)(bg * 2 + 1) * 16 + i) * 520 + f] = (_Float16)vi;
}

// ---------------- Kernel 3: MFMA flash attention (no-LDS, barrier-free) ----------------
// Per-bg K (65.7 KB) + V (33 KB) fit in L2, so LDS staging + __syncthreads are pure
// overhead (3 rounds pinned at 31% occupancy / 60% VALU / 15% Mfma with nothing
// saturated = barrier-serialization). Each wave now independently owns 16 q-rows
// (frow = chunk*64 + w*16 + qlane) and walks all K-tiles, reading K/V fragments
// DIRECT from global: per sub a wave's 64 lanes cover 16 full 128B K-rows (4 g-lanes
// x 4x8B per row) -> line-efficient, L1/L2-served. Zero barriers, zero LDS.
// XCD pinning: bg = bid % 160; 160 % 8 == 0 so all 9 chunks of a bg land on the
// same XCD; per-XCD set = 20 bgs x ~100 KB = 2 MB < 4 MB L2. Grid 1440 <= capacity
// (no LDS) so all blocks co-resident.
// Score math unchanged (log2e-scaled hi/lo fp16, mfma 16x16x32; D: q=lane&15,
// kidx=4*(lane>>4)+reg == PV B-layout; PV A=V^T rows=channel).
// Tail: tile 8 has one valid key (512): one guarded sub; OOB K lanes zeroed (score 0
// -> p underflows to 0), V explicitly zeroed (never read uninit workspace -> no NaN).
__device__ __forceinline__ void attn_step(
    half4 a0, half4 a1, half4 a2, half4 a3, half4 vfr, half4 vfi,
    const half8& Quh, const half8& Qul, const half8& Qu2h, const half8& Qu2l,
    f32x4& ore, f32x4& oim, float& m, float& l)
{
    half8 whh, wll;
#pragma unroll
    for (int j = 0; j < 4; ++j) {
        whh[j] = a0[j]; whh[4 + j] = a1[j];
        wll[j] = a2[j]; wll[4 + j] = a3[j];
    }
    f32x4 sre = {0.f, 0.f, 0.f, 0.f};
    f32x4 sim = {0.f, 0.f, 0.f, 0.f};
    sre = MFMA32(whh, Quh, sre);
    sre = MFMA32(wll, Quh, sre);
    sre = MFMA32(whh, Qul, sre);
    sre = MFMA32(wll, Qul, sre);
    sim = MFMA32(whh, Qu2h, sim);
    sim = MFMA32(wll, Qu2h, sim);
    sim = MFMA32(whh, Qu2l, sim);
    sim = MFMA32(wll, Qu2l, sim);
    float s0 = sqrtf(fmaf(sre[0], sre[0], sim[0] * sim[0]));
    float s1 = sqrtf(fmaf(sre[1], sre[1], sim[1] * sim[1]));
    float s2 = sqrtf(fmaf(sre[2], sre[2], sim[2] * sim[2]));
    float s3 = sqrtf(fmaf(sre[3], sre[3], sim[3] * sim[3]));
    float tm = fmaxf(fmaxf(s0, s1), fmaxf(s2, s3));
    tm = fmaxf(tm, __shfl_xor(tm, 16));
    tm = fmaxf(tm, __shfl_xor(tm, 32));
    if (!__all(tm <= m + 8.f)) {          // deferred rescale (T13), 8 log2-units
        float mnew  = fmaxf(m, tm);
        float alpha = exp2f(m - mnew);    // exp2(-inf)=0 covers first step
        l *= alpha; ore *= alpha; oim *= alpha;
        m = mnew;
    }
    float p0 = exp2f(s0 - m);
    float p1 = exp2f(s1 - m);
    float p2 = exp2f(s2 - m);
    float p3 = exp2f(s3 - m);
    l += (p0 + p1) + (p2 + p3);
    half4 pk;
    pk[0] = (_Float16)p0; pk[1] = (_Float16)p1;
    pk[2] = (_Float16)p2; pk[3] = (_Float16)p3;
    ore = MFMA16(vfr, pk, ore);
    oim = MFMA16(vfi, pk, oim);
}

__global__ __launch_bounds__(256, 4) void attn_kernel(const float2* __restrict__ q,
                                                      const _Float16* __restrict__ KP,
                                                      const _Float16* __restrict__ VT,
                                                      float2* __restrict__ outspec) {
    const int bg    = blockIdx.x % BG;           // XCD-pinned: bid%8 == bg%8
    const int chunk = blockIdx.x / BG;
    const int tid   = threadIdx.x;
    const int w     = tid >> 6;
    const int lane  = tid & 63;
    const int qlane = lane & 15;
    const int g     = lane >> 4;
    const int frow  = chunk * 64 + w * 16 + qlane;
    const bool writer = (frow < FDIM);
    const int f     = writer ? frow : (FDIM - 1);
    const size_t rowbase = ((size_t)bg * FDIM + f) * CDIM;

    // ---- build Q fragments (scaled by log2e): u=[qr,-qi], u'=[qi,qr] ----
    const float LOG2E = 1.44269504088896340736f;
    half8 Quh, Qul, Qu2h, Qu2l;
#pragma unroll
    for (int c = 0; c < 2; ++c) {
#pragma unroll
        for (int j = 0; j < 4; ++j) {
            const int e = 4 * c + j;
            const int k = 16 * c + 4 * g + j;
            float a = 0.f, b = 0.f;
            if (k < CDIM) {
                float2 t = q[rowbase + k];          a = t.x;  b = t.y;
            } else if (k < 2 * CDIM) {
                float2 t = q[rowbase + (k - CDIM)]; a = -t.y; b = t.x;
            }
            a *= LOG2E;
            b *= LOG2E;
            _Float16 ah = (_Float16)a;
            Quh[e]  = ah;
            Qul[e]  = (_Float16)(a - (float)ah);
            _Float16 bh = (_Float16)b;
            Qu2h[e] = bh;
            Qu2l[e] = (_Float16)(b - (float)bh);
        }
    }

    f32x4 ore = {0.f, 0.f, 0.f, 0.f};
    f32x4 oim = {0.f, 0.f, 0.f, 0.f};
    float m = -INFINITY, l = 0.f;

    const _Float16* __restrict__ KPg = KP + (size_t)bg * FDIM * 64;
    const _Float16* __restrict__ VTg = VT + (size_t)bg * 2 * 16 * 520;

    for (int t = 0; t < 8; ++t) {                // full tiles: keys 0..511
#pragma unroll
        for (int sub = 0; sub < 4; ++sub) {
            const int arow = t * 64 + sub * 16 + qlane;
            const _Float16* kr = KPg + arow * 64 + 4 * g;
            half4 a0 = *(const half4*)(kr);
            half4 a1 = *(const half4*)(kr + 16);
            half4 a2 = *(const half4*)(kr + 32);
            half4 a3 = *(const half4*)(kr + 48);
            const int f0 = t * 64 + sub * 16 + 4 * g;
            half4 vfr = *(const half4*)(VTg + qlane * 520 + f0);
            half4 vfi = *(const half4*)(VTg + (16 + qlane) * 520 + f0);
            attn_step(a0, a1, a2, a3, vfr, vfi,
                      Quh, Qul, Qu2h, Qu2l, ore, oim, m, l);
        }
    }
    {   // tail: key 512 only (rows 513..527 zeroed -> p underflows to 0)
        half4 z = {};
        half4 a0 = z, a1 = z, a2 = z, a3 = z, vfr = z, vfi = z;
        if (qlane == 0) {
            const _Float16* kr = KPg + 512 * 64 + 4 * g;
            a0 = *(const half4*)(kr);
            a1 = *(const half4*)(kr + 16);
            a2 = *(const half4*)(kr + 32);
            a3 = *(const half4*)(kr + 48);
        }
        if (g == 0) {
            vfr[0] = VTg[qlane * 520 + 512];
            vfi[0] = VTg[(16 + qlane) * 520 + 512];
        }
        attn_step(a0, a1, a2, a3, vfr, vfi,
                  Quh, Qul, Qu2h, Qu2l, ore, oim, m, l);
    }

    // ---- per-row l: sum the 4 g-group partials (intra-wave, no LDS) ----
    float lt = l;
    lt += __shfl_xor(lt, 16);
    lt += __shfl_xor(lt, 32);
    if (writer) {
        float inv = 1.f / lt;
#pragma unroll
        for (int j = 0; j < 4; ++j) {
            int c = 4 * g + j;                   // D row = channel
            if (c < CDIM)
                outspec[((size_t)(bg * CDIM + c)) * FDIM + frow] =
                    make_float2(ore[j] * inv, oim[j] * inv);
        }
    }
}

// ---------------- Kernel 4: two-for-one irfft(1024) ----------------
// Launched with 512 threads (see fft_fwd2 note).
__global__ void fft_inv2(const float2* __restrict__ spec, float* __restrict__ out) {
    __shared__ float re[1024], im[1024];
    const int s2 = blockIdx.x;                   // pair 0..1039
    const float2* Y1 = spec + (size_t)(2 * s2) * FDIM;
    const float2* Y2 = Y1 + FDIM;
    for (int t = threadIdx.x; t < 1024; t += blockDim.x) {
        float a, b, c, d;
        if (t <= 512) {
            float2 y1 = Y1[t], y2 = Y2[t];
            bool edge = (t == 0) | (t == 512);
            a = y1.x; b = edge ? 0.f : y1.y;
            c = y2.x; d = edge ? 0.f : y2.y;
        } else {
            float2 y1 = Y1[1024 - t], y2 = Y2[1024 - t];
            a = y1.x; b = -y1.y;
            c = y2.x; d = -y2.y;
        }
        unsigned r = bitrev10(t);
        re[r] = a - d;
        im[r] = b + c;
    }
    __syncthreads();
    for (int s = 0; s < 10; ++s) {
        int half = 1 << s;
        for (int j = threadIdx.x; j < 512; j += blockDim.x) {
            int grp = j >> s;
            int pos = j & (half - 1);
            int i1 = (grp << (s + 1)) + pos;
            int i2 = i1 + half;
            float ang = (float)M_PI * (float)pos / (float)half;   // +sign = inverse
            float sw, cw; __sincosf(ang, &sw, &cw);
            float xr = re[i2], xi = im[i2];
            float tr = cw * xr - sw * xi;
            float ti = cw * xi + sw * xr;
            float ur = re[i1], ui = im[i1];
            re[i1] = ur + tr; im[i1] = ui + ti;
            re[i2] = ur - tr; im[i2] = ui - ti;
        }
        __syncthreads();
    }
    const float scale = 1.0f / 1024.0f;
    float* o1 = out + (size_t)(2 * s2) * TDIM;
    for (int t = threadIdx.x; t < 1024; t += blockDim.x) {
        o1[t]        = re[t] * scale;
        o1[TDIM + t] = im[t] * scale;
    }
}

extern "C" void kernel_launch(void* const* d_in, const int* in_sizes, int n_in,
                              void* d_out, int out_size, void* d_ws, size_t ws_size,
                              hipStream_t stream) {
    const float* x  = (const float*)d_in[0];
    const float* wq = (const float*)d_in[1];
    const float* wk = (const float*)d_in[2];
    const float* wv = (const float*)d_in[3];
    float* out = (float*)d_out;

    const size_t n = (size_t)NROW * CDIM;        // 1,067,040 complex per buffer
    float2* xf = (float2*)d_ws;                  // x_fft, later reused as out-spectrum
    float2* q  = xf + n;                         // 8.54 MB
    _Float16* KP = (_Float16*)(q + n);           // NROW*64 halves = 10.51 MB
    _Float16* VT = KP + (size_t)NROW * 64;       // BG*2*16*520 halves = 5.32 MB

    fft_fwd2<<<BG * CDIM / 2, 512, 0, stream>>>(x, xf);
    qkv_kernel<<<(NROW * CDIM + 255) / 256, 256, 0, stream>>>(xf, wq, wk, wv, q, KP, VT);
    attn_kernel<<<BG * NCHUNK, 256, 0, stream>>>(q, KP, VT, xf /* outspec, aliases xf */);
    fft_inv2<<<BG * CDIM / 2, 512, 0, stream>>>(xf, out);
}

// Round 9
// 226.971 us; speedup vs baseline: 1.0196x; 1.0196x over previous
//
#include <hip/hip_runtime.h>
#include <math.h>

// Problem constants
#define BDIM 4
#define GDIM 40
#define CDIM 13
#define TDIM 1024
#define FDIM 513                 // T/2 + 1
#define BG   (BDIM*GDIM)         // 160
#define NROW (BG*FDIM)           // 82080 rows of [13] complex
#define NCHUNK 9                 // 9*64 = 576 >= 513 q-rows per bg

typedef _Float16 half4 __attribute__((ext_vector_type(4)));
typedef _Float16 half8 __attribute__((ext_vector_type(8)));
typedef float    f32x4 __attribute__((ext_vector_type(4)));

#define MFMA16(a, b, c) __builtin_amdgcn_mfma_f32_16x16x16f16((a), (b), (c), 0, 0, 0)
#define MFMA32(a, b, c) __builtin_amdgcn_mfma_f32_16x16x32_f16((a), (b), (c), 0, 0, 0)

__device__ __forceinline__ unsigned bitrev10(unsigned x) { return __brev(x) >> 22; }

// ---------------- Kernel 1: two-for-one rfft(1024) ----------------
// Launched with 512 threads: 1 butterfly per thread per stage, 8 waves/block.
__global__ void fft_fwd2(const float* __restrict__ x, float2* __restrict__ xf) {
    __shared__ float re[1024], im[1024];
    const int s2 = blockIdx.x;                   // pair index, 0..1039
    const float* x1 = x + (size_t)(2 * s2) * TDIM;
    const float* x2 = x1 + TDIM;
    for (int t = threadIdx.x; t < 1024; t += blockDim.x) {
        unsigned r = bitrev10(t);
        re[r] = x1[t];
        im[r] = x2[t];
    }
    __syncthreads();
    for (int s = 0; s < 10; ++s) {
        int half = 1 << s;
        for (int j = threadIdx.x; j < 512; j += blockDim.x) {
            int grp = j >> s;
            int pos = j & (half - 1);
            int i1 = (grp << (s + 1)) + pos;
            int i2 = i1 + half;
            float ang = -(float)M_PI * (float)pos / (float)half;
            float sw, cw; __sincosf(ang, &sw, &cw);
            float xr = re[i2], xi = im[i2];
            float tr = cw * xr - sw * xi;
            float ti = cw * xi + sw * xr;
            float ur = re[i1], ui = im[i1];
            re[i1] = ur + tr; im[i1] = ui + ti;
            re[i2] = ur - tr; im[i2] = ui - ti;
        }
        __syncthreads();
    }
    const int sigA = 2 * s2, sigB = sigA + 1;
    const int bgA = sigA / CDIM, cA = sigA % CDIM;
    const int bgB = sigB / CDIM, cB = sigB % CDIM;
    for (int f = threadIdx.x; f < FDIM; f += blockDim.x) {
        int fr = (1024 - f) & 1023;
        float zr = re[f], zi = im[f];
        float wr = re[fr], wi = im[fr];
        xf[((size_t)bgA * FDIM + f) * CDIM + cA] =
            make_float2(0.5f * (zr + wr), 0.5f * (zi - wi));
        xf[((size_t)bgB * FDIM + f) * CDIM + cB] =
            make_float2(0.5f * (zi + wi), 0.5f * (wr - zr));
    }
}

// ---------------- Kernel 2: Q/K/V projections ----------------
// q: float2 rows (for in-reg Q-fragment build in attn).
// KP: per row 64 halves [hi(kr)0..12 | hi(ki)@13..25 | 0 @26..31 | lo(kr)@32..44 | lo(ki)@45..57 | 0 @58..63]
// VT: fp16, transposed: [bg][re/im][c(16)][f stride 520]
__global__ void qkv_kernel(const float2* __restrict__ xf,
                           const float* __restrict__ wq,
                           const float* __restrict__ wk,
                           const float* __restrict__ wv,
                           float2* __restrict__ q,
                           _Float16* __restrict__ KP,
                           _Float16* __restrict__ VT) {
    int gid = blockIdx.x * blockDim.x + threadIdx.x;
    if (gid >= NROW * CDIM) return;
    int r = gid / CDIM;
    int i = gid - r * CDIM;
    const float2* xrow = xf + (size_t)r * CDIM;
    float qr = 0, qi = 0, kr = 0, ki = 0, vr = 0, vi = 0;
#pragma unroll
    for (int c = 0; c < CDIM; ++c) {
        float2 xc = xrow[c];
        float a = wq[c * CDIM + i]; qr += xc.x * a; qi += xc.y * a;
        float b = wk[c * CDIM + i]; kr += xc.x * b; ki += xc.y * b;
        float d = wv[c * CDIM + i]; vr += xc.x * d; vi += xc.y * d;
    }
    q[gid] = make_float2(qr, qi);

    _Float16* krow = KP + (size_t)r * 64;
    _Float16 h0 = (_Float16)kr;
    _Float16 h1 = (_Float16)ki;
    krow[i]      = h0;
    krow[13 + i] = h1;
    krow[32 + i] = (_Float16)(kr - (float)h0);
    krow[45 + i] = (_Float16)(ki - (float)h1);
    if (i == 12) {   // zero the pad halves 26..31 and 58..63
        *(unsigned int*)(krow + 26) = 0u;
        *(unsigned int*)(krow + 28) = 0u;
        *(unsigned int*)(krow + 30) = 0u;
        *(unsigned int*)(krow + 58) = 0u;
        *(unsigned int*)(krow + 60) = 0u;
        *(unsigned int*)(krow + 62) = 0u;
    }
    int bg = r / FDIM;
    int f  = r - bg * FDIM;
    VT[((size_t)(bg * 2 + 0) * 16 + i) * 520 + f] = (_Float16)vr;
    VT[((size_t)(bg * 2 + 1) * 16 + i) * 520 + f] = (_Float16)vi;
}

// ---------------- Kernel 3: MFMA flash attention (no-LDS + reg prefetch) ----------------
// r8 lesson: direct-global fragments cut FETCH 68.7->13.1 MB (L2-pinned) but put
// load latency on the critical path (VALUBusy 41%, every sub-step stalls on vmcnt).
// Fix (T14/G7): 1-deep software pipeline — issue sub-step s+1's 6x8B fragment loads
// BEFORE computing sub-step s; the ~130cy of MFMA+softmax covers L1/L2 latency.
// Named-register rotation (rule #20: no runtime-indexed frag arrays). +12 VGPR.
// Everything else as r8: barrier-free, no LDS, XCD-pinned (bg = bid % 160),
// log2-domain softmax, deferred rescale, tail key 512 guarded.
__device__ __forceinline__ void attn_step(
    half4 a0, half4 a1, half4 a2, half4 a3, half4 vfr, half4 vfi,
    const half8& Quh, const half8& Qul, const half8& Qu2h, const half8& Qu2l,
    f32x4& ore, f32x4& oim, float& m, float& l)
{
    half8 whh, wll;
#pragma unroll
    for (int j = 0; j < 4; ++j) {
        whh[j] = a0[j]; whh[4 + j] = a1[j];
        wll[j] = a2[j]; wll[4 + j] = a3[j];
    }
    f32x4 sre = {0.f, 0.f, 0.f, 0.f};
    f32x4 sim = {0.f, 0.f, 0.f, 0.f};
    sre = MFMA32(whh, Quh, sre);
    sre = MFMA32(wll, Quh, sre);
    sre = MFMA32(whh, Qul, sre);
    sre = MFMA32(wll, Qul, sre);
    sim = MFMA32(whh, Qu2h, sim);
    sim = MFMA32(wll, Qu2h, sim);
    sim = MFMA32(whh, Qu2l, sim);
    sim = MFMA32(wll, Qu2l, sim);
    float s0 = sqrtf(fmaf(sre[0], sre[0], sim[0] * sim[0]));
    float s1 = sqrtf(fmaf(sre[1], sre[1], sim[1] * sim[1]));
    float s2 = sqrtf(fmaf(sre[2], sre[2], sim[2] * sim[2]));
    float s3 = sqrtf(fmaf(sre[3], sre[3], sim[3] * sim[3]));
    float tm = fmaxf(fmaxf(s0, s1), fmaxf(s2, s3));
    tm = fmaxf(tm, __shfl_xor(tm, 16));
    tm = fmaxf(tm, __shfl_xor(tm, 32));
    if (!__all(tm <= m + 8.f)) {          // deferred rescale (T13), 8 log2-units
        float mnew  = fmaxf(m, tm);
        float alpha = exp2f(m - mnew);    // exp2(-inf)=0 covers first step
        l *= alpha; ore *= alpha; oim *= alpha;
        m = mnew;
    }
    float p0 = exp2f(s0 - m);
    float p1 = exp2f(s1 - m);
    float p2 = exp2f(s2 - m);
    float p3 = exp2f(s3 - m);
    l += (p0 + p1) + (p2 + p3);
    half4 pk;
    pk[0] = (_Float16)p0; pk[1] = (_Float16)p1;
    pk[2] = (_Float16)p2; pk[3] = (_Float16)p3;
    ore = MFMA16(vfr, pk, ore);
    oim = MFMA16(vfi, pk, oim);
}

__device__ __forceinline__ void load_frag(
    const _Float16* __restrict__ KPg, const _Float16* __restrict__ VTg,
    int s, int qlane, int g,
    half4& a0, half4& a1, half4& a2, half4& a3, half4& vfr, half4& vfi)
{
    const int arow = s * 16 + qlane;
    const _Float16* kr = KPg + arow * 64 + 4 * g;
    a0 = *(const half4*)(kr);
    a1 = *(const half4*)(kr + 16);
    a2 = *(const half4*)(kr + 32);
    a3 = *(const half4*)(kr + 48);
    const int f0 = s * 16 + 4 * g;
    vfr = *(const half4*)(VTg + qlane * 520 + f0);
    vfi = *(const half4*)(VTg + (16 + qlane) * 520 + f0);
}

__global__ __launch_bounds__(256, 4) void attn_kernel(const float2* __restrict__ q,
                                                      const _Float16* __restrict__ KP,
                                                      const _Float16* __restrict__ VT,
                                                      float2* __restrict__ outspec) {
    const int bg    = blockIdx.x % BG;           // XCD-pinned: bid%8 == bg%8
    const int chunk = blockIdx.x / BG;
    const int tid   = threadIdx.x;
    const int w     = tid >> 6;
    const int lane  = tid & 63;
    const int qlane = lane & 15;
    const int g     = lane >> 4;
    const int frow  = chunk * 64 + w * 16 + qlane;
    const bool writer = (frow < FDIM);
    const int f     = writer ? frow : (FDIM - 1);
    const size_t rowbase = ((size_t)bg * FDIM + f) * CDIM;

    // ---- build Q fragments (scaled by log2e): u=[qr,-qi], u'=[qi,qr] ----
    const float LOG2E = 1.44269504088896340736f;
    half8 Quh, Qul, Qu2h, Qu2l;
#pragma unroll
    for (int c = 0; c < 2; ++c) {
#pragma unroll
        for (int j = 0; j < 4; ++j) {
            const int e = 4 * c + j;
            const int k = 16 * c + 4 * g + j;
            float a = 0.f, b = 0.f;
            if (k < CDIM) {
                float2 t = q[rowbase + k];          a = t.x;  b = t.y;
            } else if (k < 2 * CDIM) {
                float2 t = q[rowbase + (k - CDIM)]; a = -t.y; b = t.x;
            }
            a *= LOG2E;
            b *= LOG2E;
            _Float16 ah = (_Float16)a;
            Quh[e]  = ah;
            Qul[e]  = (_Float16)(a - (float)ah);
            _Float16 bh = (_Float16)b;
            Qu2h[e] = bh;
            Qu2l[e] = (_Float16)(b - (float)bh);
        }
    }

    f32x4 ore = {0.f, 0.f, 0.f, 0.f};
    f32x4 oim = {0.f, 0.f, 0.f, 0.f};
    float m = -INFINITY, l = 0.f;

    const _Float16* __restrict__ KPg = KP + (size_t)bg * FDIM * 64;
    const _Float16* __restrict__ VTg = VT + (size_t)bg * 2 * 16 * 520;

    // ---- software-pipelined walk over the 32 full sub-steps (keys 0..511) ----
    half4 ca0, ca1, ca2, ca3, cvr, cvi;
    load_frag(KPg, VTg, 0, qlane, g, ca0, ca1, ca2, ca3, cvr, cvi);
    for (int s = 0; s < 31; ++s) {
        half4 na0, na1, na2, na3, nvr, nvi;
        load_frag(KPg, VTg, s + 1, qlane, g, na0, na1, na2, na3, nvr, nvi);
        attn_step(ca0, ca1, ca2, ca3, cvr, cvi,
                  Quh, Qul, Qu2h, Qu2l, ore, oim, m, l);
        ca0 = na0; ca1 = na1; ca2 = na2; ca3 = na3; cvr = nvr; cvi = nvi;
    }
    attn_step(ca0, ca1, ca2, ca3, cvr, cvi,
              Quh, Qul, Qu2h, Qu2l, ore, oim, m, l);

    {   // tail: key 512 only (rows 513..527 zeroed -> p underflows to 0)
        half4 z = {};
        half4 a0 = z, a1 = z, a2 = z, a3 = z, vfr = z, vfi = z;
        if (qlane == 0) {
            const _Float16* kr = KPg + 512 * 64 + 4 * g;
            a0 = *(const half4*)(kr);
            a1 = *(const half4*)(kr + 16);
            a2 = *(const half4*)(kr + 32);
            a3 = *(const half4*)(kr + 48);
        }
        if (g == 0) {
            vfr[0] = VTg[qlane * 520 + 512];
            vfi[0] = VTg[(16 + qlane) * 520 + 512];
        }
        attn_step(a0, a1, a2, a3, vfr, vfi,
                  Quh, Qul, Qu2h, Qu2l, ore, oim, m, l);
    }

    // ---- per-row l: sum the 4 g-group partials (intra-wave, no LDS) ----
    float lt = l;
    lt += __shfl_xor(lt, 16);
    lt += __shfl_xor(lt, 32);
    if (writer) {
        float inv = 1.f / lt;
#pragma unroll
        for (int j = 0; j < 4; ++j) {
            int c = 4 * g + j;                   // D row = channel
            if (c < CDIM)
                outspec[((size_t)(bg * CDIM + c)) * FDIM + frow] =
                    make_float2(ore[j] * inv, oim[j] * inv);
        }
    }
}

// ---------------- Kernel 4: two-for-one irfft(1024) ----------------
// Launched with 512 threads (see fft_fwd2 note).
__global__ void fft_inv2(const float2* __restrict__ spec, float* __restrict__ out) {
    __shared__ float re[1024], im[1024];
    const int s2 = blockIdx.x;                   // pair 0..1039
    const float2* Y1 = spec + (size_t)(2 * s2) * FDIM;
    const float2* Y2 = Y1 + FDIM;
    for (int t = threadIdx.x; t < 1024; t += blockDim.x) {
        float a, b, c, d;
        if (t <= 512) {
            float2 y1 = Y1[t], y2 = Y2[t];
            bool edge = (t == 0) | (t == 512);
            a = y1.x; b = edge ? 0.f : y1.y;
            c = y2.x; d = edge ? 0.f : y2.y;
        } else {
            float2 y1 = Y1[1024 - t], y2 = Y2[1024 - t];
            a = y1.x; b = -y1.y;
            c = y2.x; d = -y2.y;
        }
        unsigned r = bitrev10(t);
        re[r] = a - d;
        im[r] = b + c;
    }
    __syncthreads();
    for (int s = 0; s < 10; ++s) {
        int half = 1 << s;
        for (int j = threadIdx.x; j < 512; j += blockDim.x) {
            int grp = j >> s;
            int pos = j & (half - 1);
            int i1 = (grp << (s + 1)) + pos;
            int i2 = i1 + half;
            float ang = (float)M_PI * (float)pos / (float)half;   // +sign = inverse
            float sw, cw; __sincosf(ang, &sw, &cw);
            float xr = re[i2], xi = im[i2];
            float tr = cw * xr - sw * xi;
            float ti = cw * xi + sw * xr;
            float ur = re[i1], ui = im[i1];
            re[i1] = ur + tr; im[i1] = ui + ti;
            re[i2] = ur - tr; im[i2] = ui - ti;
        }
        __syncthreads();
    }
    const float scale = 1.0f / 1024.0f;
    float* o1 = out + (size_t)(2 * s2) * TDIM;
    for (int t = threadIdx.x; t < 1024; t += blockDim.x) {
        o1[t]        = re[t] * scale;
        o1[TDIM + t] = im[t] * scale;
    }
}

extern "C" void kernel_launch(void* const* d_in, const int* in_sizes, int n_in,
                              void* d_out, int out_size, void* d_ws, size_t ws_size,
                              hipStream_t stream) {
    const float* x  = (const float*)d_in[0];
    const float* wq = (const float*)d_in[1];
    const float* wk = (const float*)d_in[2];
    const float* wv = (const float*)d_in[3];
    float* out = (float*)d_out;

    const size_t n = (size_t)NROW * CDIM;        // 1,067,040 complex per buffer
    float2* xf = (float2*)d_ws;                  // x_fft, later reused as out-spectrum
    float2* q  = xf + n;                         // 8.54 MB
    _Float16* KP = (_Float16*)(q + n);           // NROW*64 halves = 10.51 MB
    _Float16* VT = KP + (size_t)NROW * 64;       // BG*2*16*520 halves = 5.32 MB

    fft_fwd2<<<BG * CDIM / 2, 512, 0, stream>>>(x, xf);
    qkv_kernel<<<(NROW * CDIM + 255) / 256, 256, 0, stream>>>(xf, wq, wk, wv, q, KP, VT);
    attn_kernel<<<BG * NCHUNK, 256, 0, stream>>>(q, KP, VT, xf /* outspec, aliases xf */);
    fft_inv2<<<BG * CDIM / 2, 512, 0, stream>>>(xf, out);
}